// Round 8
// baseline (94.827 us; speedup 1.0000x reference)
//
#include <hip/hip_runtime.h>

#define BB 8
#define XX 256
#define CC 256
#define TCD 8         // c-rows per k_main block
#define TCE 4         // c-rows per fallback block
#define G  8          // x-group size for the register double-buffer pipeline
#define NCH 4         // x-chunks per block (thread dim z)
#define XH (XX / NCH) // 64

// R8: fuse dist+epilogue into one 1024-thread kernel. Per-(c,d,chunk) Gram
// chain, chunk-combine order, and epilogue transcendental chain are all
// bitwise-identical to R7 (which scored absmax 0.0); partials move through
// LDS instead of a 16 MB global round-trip, killing one dispatch + gap.

// ---------------- Path A ----------------

// k_u: u = wa*amp + wp*ph for all B*X*C; blocks 0..63 also zero `out`.
__global__ __launch_bounds__(256) void k_u(
    const float* __restrict__ amp, const float* __restrict__ ph,
    const float* __restrict__ wAp, const float* __restrict__ wPp,
    float* __restrict__ u, float* __restrict__ out)
{
    const float wa = wAp[0], wp = wPp[0];
    const int i = blockIdx.x * 256 + threadIdx.x;   // float4 index, exact cover
    const float4 a = ((const float4*)amp)[i];
    const float4 p = ((const float4*)ph)[i];
    float4 r;
    r.x = __fadd_rn(__fmul_rn(wa, a.x), __fmul_rn(wp, p.x));
    r.y = __fadd_rn(__fmul_rn(wa, a.y), __fmul_rn(wp, p.y));
    r.z = __fadd_rn(__fmul_rn(wa, a.z), __fmul_rn(wp, p.z));
    r.w = __fadd_rn(__fmul_rn(wa, a.w), __fmul_rn(wp, p.w));
    ((float4*)u)[i] = r;

    if (blockIdx.x < 64) {            // 64 blocks * 256 thr * 16B = 256 KB = out
        ((float4*)out)[blockIdx.x * 256 + threadIdx.x] = make_float4(0.f, 0.f, 0.f, 0.f);
    }
}

#define ULOAD(BU, GIDX) {                                  \
    const float* _p = ud_ptr + (size_t)(GIDX) * G * CC;    \
    _Pragma("unroll")                                      \
    for (int i = 0; i < G; ++i) BU[i] = _p[(size_t)i * CC]; }

#define UCOMP(BU, GIDX) {                                  \
    const int _xb = x0 + (GIDX) * G;                       \
    _Pragma("unroll")                                      \
    for (int i = 0; i < G; ++i) {                          \
        const float udv = BU[i];                           \
        const float4 cA = colsU[_xb + i][0];               \
        const float4 cB = colsU[_xb + i][1];               \
        gacc0 = fmaf(cA.x, udv, gacc0);                    \
        gacc1 = fmaf(cA.y, udv, gacc1);                    \
        gacc2 = fmaf(cA.z, udv, gacc2);                    \
        gacc3 = fmaf(cA.w, udv, gacc3);                    \
        gacc4 = fmaf(cB.x, udv, gacc4);                    \
        gacc5 = fmaf(cB.y, udv, gacc5);                    \
        gacc6 = fmaf(cB.z, udv, gacc6);                    \
        gacc7 = fmaf(cB.w, udv, gacc7);                    \
        sacc  = fmaf(udv, udv, sacc);                      \
    } }

__global__ __launch_bounds__(1024, 4) void k_main(
    const float* __restrict__ u,      // (B,X,C) in ws
    const float* __restrict__ A,
    const float* __restrict__ gu,
    float* __restrict__ out)
{
    const int tid = threadIdx.x;
    const int c0  = blockIdx.x * TCD;
    const int b   = blockIdx.y;

    __shared__ float4 colsU[XX][2];      // u[b, x, c0..c0+7]       8 KB
    __shared__ float  sS[NCH][CC];       // per-chunk S_d            4 KB
    __shared__ float  pw[NCH][CC][9];    // per-chunk partials      36 KB (pad 9)
    __shared__ float  wmax[TCD][4];

    // stage the 8 c-columns of u (bitwise same values as R7's colsU)
    if (tid < 512) {
        const int x = tid >> 1, h = tid & 1;
        colsU[x][h] = *(const float4*)(u + ((size_t)b * XX + x) * CC + c0 + 4 * h);
    }
    __syncthreads();

    const int d     = tid & 255;
    const int chunk = tid >> 8;          // 0..3
    const int x0    = chunk * XH;

    const float* ud_ptr = u + ((size_t)b * XX + x0) * CC + d;

    float gacc0=0.f, gacc1=0.f, gacc2=0.f, gacc3=0.f;
    float gacc4=0.f, gacc5=0.f, gacc6=0.f, gacc7=0.f, sacc=0.f;

    constexpr int NGH = XH / G;          // 8
    {
        float b0[G], b1[G];
        ULOAD(b0, 0)
        for (int g = 0; g + 2 < NGH; g += 2) {
            ULOAD(b1, g + 1)
            UCOMP(b0, g)
            ULOAD(b0, g + 2)
            UCOMP(b1, g + 1)
        }
        ULOAD(b1, NGH - 1)
        UCOMP(b0, NGH - 2)
        UCOMP(b1, NGH - 1)
    }

    // per-chunk S exchange (same values/order as R7 k_dist)
    sS[chunk][d] = sacc;
    __syncthreads();

    // per-chunk partials, bitwise R7: fmaf(-2, G, S_c + S_d)
    pw[chunk][d][0] = fmaf(-2.0f, gacc0, __fadd_rn(sS[chunk][c0 + 0], sacc));
    pw[chunk][d][1] = fmaf(-2.0f, gacc1, __fadd_rn(sS[chunk][c0 + 1], sacc));
    pw[chunk][d][2] = fmaf(-2.0f, gacc2, __fadd_rn(sS[chunk][c0 + 2], sacc));
    pw[chunk][d][3] = fmaf(-2.0f, gacc3, __fadd_rn(sS[chunk][c0 + 3], sacc));
    pw[chunk][d][4] = fmaf(-2.0f, gacc4, __fadd_rn(sS[chunk][c0 + 4], sacc));
    pw[chunk][d][5] = fmaf(-2.0f, gacc5, __fadd_rn(sS[chunk][c0 + 5], sacc));
    pw[chunk][d][6] = fmaf(-2.0f, gacc6, __fadd_rn(sS[chunk][c0 + 6], sacc));
    pw[chunk][d][7] = fmaf(-2.0f, gacc7, __fadd_rn(sS[chunk][c0 + 7], sacc));
    __syncthreads();

    // ---- fused epilogue: thread (de, j2) handles rows j = 2*j2, 2*j2+1 ----
    const int de   = tid & 255;
    const int j2   = tid >> 8;           // 0..3
    const int wv   = (tid >> 6) & 3;     // wave within j2-group
    const int lane = tid & 63;

    const float dAd  = A[(size_t)de * CC + de];
    const float dAd2 = __fmul_rn(dAd, dAd);

    float edv[2];
#pragma unroll
    for (int k = 0; k < 2; ++k) {
        const int j = 2 * j2 + k;
        // sequential chunk combine, same order as R7 k_epi (h = 0..3)
        float p = pw[0][de][j];
        p = __fadd_rn(p, pw[1][de][j]);
        p = __fadd_rn(p, pw[2][de][j]);
        p = __fadd_rn(p, pw[3][de][j]);
        const float dist = __fmul_rn(dAd2, p);
        edv[k] = (de == c0 + j) ? 0.0f : __fdiv_rn(1.0f, __fadd_rn(dist, 1e-10f));
    }

#pragma unroll
    for (int k = 0; k < 2; ++k) {
        float v = edv[k];
#pragma unroll
        for (int m = 1; m < 64; m <<= 1) v = fmaxf(v, __shfl_xor(v, m));
        if (lane == 0) wmax[2 * j2 + k][wv] = v;
    }
    __syncthreads();

#pragma unroll
    for (int k = 0; k < 2; ++k) {
        const int j = 2 * j2 + k;
        const int c = c0 + j;
        float em = fmaxf(fmaxf(wmax[j][0], wmax[j][1]), fmaxf(wmax[j][2], wmax[j][3]));
        float p;
        if (de == c) {
            p = 0.99f;
        } else {
            p = __fmul_rn(__fdiv_rn(edv[k], em), 0.99f);
        }
        float logit = logf(__fdiv_rn(p, __fsub_rn(1.0f, p)));

        const float2 g2 = *(const float2*)(gu + (((size_t)b * CC + c) * CC + de) * 2);
        float g0 = -logf(-logf(g2.x));
        float g1 = -logf(-logf(g2.y));

        float a0 = __fadd_rn(logit, g0);
        float a1 = __fadd_rn(-logit, g1);
        float m  = fmaxf(a0, a1);
        float e0 = expf(__fsub_rn(a0, m));
        float e1 = expf(__fsub_rn(a1, m));
        float s  = __fadd_rn(e0, e1);
        float y0 = __fdiv_rn(e0, s);
        float y1 = __fdiv_rn(e1, s);
        if (y0 > y1) {
            atomicAdd(&out[(size_t)c * CC + de], 0.125f);
        }
    }
}

// ---------------- Path B: fused fallback (no ws) — R7 verbatim ----------------

__device__ __forceinline__ void epilogue4(
    float dist0, float dist1, float dist2, float dist3,
    int b, int c0, int d, const float* __restrict__ gu,
    float* __restrict__ out, float (*wmax)[4])
{
    float ed[TCE];
    ed[0] = (d == c0)     ? 0.0f : __fdiv_rn(1.0f, __fadd_rn(dist0, 1e-10f));
    ed[1] = (d == c0 + 1) ? 0.0f : __fdiv_rn(1.0f, __fadd_rn(dist1, 1e-10f));
    ed[2] = (d == c0 + 2) ? 0.0f : __fdiv_rn(1.0f, __fadd_rn(dist2, 1e-10f));
    ed[3] = (d == c0 + 3) ? 0.0f : __fdiv_rn(1.0f, __fadd_rn(dist3, 1e-10f));

    const int wave = threadIdx.x >> 6;
    const int lane = threadIdx.x & 63;
#pragma unroll
    for (int j = 0; j < TCE; ++j) {
        float v = ed[j];
#pragma unroll
        for (int m = 1; m < 64; m <<= 1) v = fmaxf(v, __shfl_xor(v, m));
        if (lane == 0) wmax[j][wave] = v;
    }
    __syncthreads();

#pragma unroll
    for (int j = 0; j < TCE; ++j) {
        const int c = c0 + j;
        float em = fmaxf(fmaxf(wmax[j][0], wmax[j][1]), fmaxf(wmax[j][2], wmax[j][3]));
        float p;
        if (d == c) {
            p = 0.99f;
        } else {
            p = __fmul_rn(__fdiv_rn(ed[j], em), 0.99f);
        }
        float logit = logf(__fdiv_rn(p, __fsub_rn(1.0f, p)));

        const float2 g2 = *(const float2*)(gu + (((size_t)b * CC + c) * CC + d) * 2);
        float g0 = -logf(-logf(g2.x));
        float g1 = -logf(-logf(g2.y));

        float a0 = __fadd_rn(logit, g0);
        float a1 = __fadd_rn(-logit, g1);
        float m  = fmaxf(a0, a1);
        float e0 = expf(__fsub_rn(a0, m));
        float e1 = expf(__fsub_rn(a1, m));
        float s  = __fadd_rn(e0, e1);
        float y0 = __fdiv_rn(e0, s);
        float y1 = __fdiv_rn(e1, s);
        if (y0 > y1) {
            atomicAdd(&out[(size_t)c * CC + d], 0.125f);
        }
    }
}

#define STEPU(UC, ACC) {                         \
    float diff = __fsub_rn(UC, ud);              \
    float t    = __fmul_rn(dAd, diff);           \
    float sq   = __fmul_rn(t, t);                \
    ACC = __fadd_rn(ACC, sq);                    \
}

#define LOADG(BA, BP, GIDX) {                    \
    const float* _a = ampbd + (size_t)(GIDX) * G * CC; \
    const float* _p = phbd  + (size_t)(GIDX) * G * CC; \
    _Pragma("unroll")                            \
    for (int i = 0; i < G; ++i) {                \
        BA[i] = _a[(size_t)i * CC];              \
        BP[i] = _p[(size_t)i * CC];              \
    }                                            \
}

#define COMPG(BA, BP, GIDX) {                    \
    const int _xb = (GIDX) * G;                  \
    _Pragma("unroll")                            \
    for (int i = 0; i < G; ++i) {                \
        const float av = BA[i];                  \
        const float pv = BP[i];                  \
        const float ud = __fadd_rn(__fmul_rn(wa, av), __fmul_rn(wp, pv)); \
        const float4 uc = cols[_xb + i];         \
        STEPU(uc.x, acc0)                        \
        STEPU(uc.y, acc1)                        \
        STEPU(uc.z, acc2)                        \
        STEPU(uc.w, acc3)                        \
    }                                            \
}

__global__ __launch_bounds__(256, 2) void k_fused(
    const float* __restrict__ amp, const float* __restrict__ ph,
    const float* __restrict__ A,   const float* __restrict__ wAp,
    const float* __restrict__ wPp, const float* __restrict__ gu,
    float* __restrict__ out)
{
    const int d  = threadIdx.x;
    const int c0 = blockIdx.x * TCE;
    const int b  = blockIdx.y;

    const float wa = wAp[0];
    const float wp = wPp[0];

    __shared__ float4 cols[XX];
    {
        const int x = threadIdx.x;
        const size_t base = ((size_t)b * XX + x) * CC + c0;
        const float4 a4 = *(const float4*)(amp + base);
        const float4 p4 = *(const float4*)(ph  + base);
        float4 uu;
        uu.x = __fadd_rn(__fmul_rn(wa, a4.x), __fmul_rn(wp, p4.x));
        uu.y = __fadd_rn(__fmul_rn(wa, a4.y), __fmul_rn(wp, p4.y));
        uu.z = __fadd_rn(__fmul_rn(wa, a4.z), __fmul_rn(wp, p4.z));
        uu.w = __fadd_rn(__fmul_rn(wa, a4.w), __fmul_rn(wp, p4.w));
        cols[x] = uu;
    }
    __syncthreads();

    const float dAd = A[(size_t)d * CC + d];
    const float* ampbd = amp + (size_t)b * XX * CC + d;
    const float* phbd  = ph  + (size_t)b * XX * CC + d;

    float acc0 = 0.0f, acc1 = 0.0f, acc2 = 0.0f, acc3 = 0.0f;
    constexpr int NG = XX / G;
    {
        float b0A[G], b0P[G], b1A[G], b1P[G];
        LOADG(b0A, b0P, 0)
        for (int g = 0; g + 2 < NG; g += 2) {
            LOADG(b1A, b1P, g + 1)
            COMPG(b0A, b0P, g)
            LOADG(b0A, b0P, g + 2)
            COMPG(b1A, b1P, g + 1)
        }
        LOADG(b1A, b1P, NG - 1)
        COMPG(b0A, b0P, NG - 2)
        COMPG(b1A, b1P, NG - 1)
    }

    __shared__ float wmax[TCE][4];
    epilogue4(acc0, acc1, acc2, acc3, b, c0, d, gu, out, wmax);
}

extern "C" void kernel_launch(void* const* d_in, const int* in_sizes, int n_in,
                              void* d_out, int out_size, void* d_ws, size_t ws_size,
                              hipStream_t stream) {
    const float* amp = (const float*)d_in[0];
    const float* ph  = (const float*)d_in[1];
    const float* A   = (const float*)d_in[2];
    const float* wa  = (const float*)d_in[3];
    const float* wp  = (const float*)d_in[4];
    const float* gu  = (const float*)d_in[5];
    float* out = (float*)d_out;

    const size_t uElems = (size_t)BB * XX * CC;            // 2 MB
    const size_t need = uElems * sizeof(float);
    if (ws_size >= need) {
        float* ud = (float*)d_ws;       // fully written by k_u every launch
        k_u<<<uElems / 4 / 256, 256, 0, stream>>>(amp, ph, wa, wp, ud, out);
        dim3 g(CC / TCD, BB);
        k_main<<<g, 1024, 0, stream>>>(ud, A, gu, out);
    } else {
        hipMemsetAsync(out, 0, (size_t)CC * CC * sizeof(float), stream);
        dim3 g(CC / TCE, BB);
        k_fused<<<g, 256, 0, stream>>>(amp, ph, A, wa, wp, gu, out);
    }
}

// Round 9
// 84.441 us; speedup vs baseline: 1.1230x; 1.1230x over previous
//
#include <hip/hip_runtime.h>

#define BB 8
#define XX 256
#define CC 256
#define TCD 8         // c-rows per k_dist block
#define TCE 4         // c-rows per k_epi block
#define G  8          // x-group size for the register double-buffer pipeline
#define SPLIT 4       // x-split for k_dist
#define XH (XX / SPLIT)

// R9 = R7 bitwise, minus k_dist's LDS c-column staging. The c-values are
// wave-uniform -> direct global reads (compiler: s_load on the scalar pipe;
// worst case L1-broadcast VMEM). R6/R7/R8 all carried ~10.2 us of
// ds_read_b128 serialization (524288 instrs / 256 CU x 12 cyc) — that was
// the invariant bottleneck, now removed. wsd and out stay bitwise R7.

// ---------------- Path A ----------------

// k_u: u = wa*amp + wp*ph for all B*X*C; blocks 0..63 also zero `out`.
__global__ __launch_bounds__(256) void k_u(
    const float* __restrict__ amp, const float* __restrict__ ph,
    const float* __restrict__ wAp, const float* __restrict__ wPp,
    float* __restrict__ u, float* __restrict__ out)
{
    const float wa = wAp[0], wp = wPp[0];
    const int i = blockIdx.x * 256 + threadIdx.x;   // float4 index, exact cover
    const float4 a = ((const float4*)amp)[i];
    const float4 p = ((const float4*)ph)[i];
    float4 r;
    r.x = __fadd_rn(__fmul_rn(wa, a.x), __fmul_rn(wp, p.x));
    r.y = __fadd_rn(__fmul_rn(wa, a.y), __fmul_rn(wp, p.y));
    r.z = __fadd_rn(__fmul_rn(wa, a.z), __fmul_rn(wp, p.z));
    r.w = __fadd_rn(__fmul_rn(wa, a.w), __fmul_rn(wp, p.w));
    ((float4*)u)[i] = r;

    if (blockIdx.x < 64) {            // 64 blocks * 256 thr * 16B = 256 KB = out
        ((float4*)out)[blockIdx.x * 256 + threadIdx.x] = make_float4(0.f, 0.f, 0.f, 0.f);
    }
}

#define ULOAD(BU, GIDX) {                                  \
    const float* _p = ud_ptr + (size_t)(GIDX) * G * CC;    \
    _Pragma("unroll")                                      \
    for (int i = 0; i < G; ++i) BU[i] = _p[(size_t)i * CC]; }

// c-values read straight from global at a wave-uniform address (no LDS).
#define UCOMP(BU, GIDX) {                                  \
    const int _xb = (GIDX) * G;                            \
    _Pragma("unroll")                                      \
    for (int i = 0; i < G; ++i) {                          \
        const float udv = BU[i];                           \
        const float4 cA = *(const float4*)(ucol + (size_t)(_xb + i) * CC);     \
        const float4 cB = *(const float4*)(ucol + (size_t)(_xb + i) * CC + 4); \
        gacc0 = fmaf(cA.x, udv, gacc0);                    \
        gacc1 = fmaf(cA.y, udv, gacc1);                    \
        gacc2 = fmaf(cA.z, udv, gacc2);                    \
        gacc3 = fmaf(cA.w, udv, gacc3);                    \
        gacc4 = fmaf(cB.x, udv, gacc4);                    \
        gacc5 = fmaf(cB.y, udv, gacc5);                    \
        gacc6 = fmaf(cB.z, udv, gacc6);                    \
        gacc7 = fmaf(cB.w, udv, gacc7);                    \
        sacc  = fmaf(udv, udv, sacc);                      \
    } }

__global__ __launch_bounds__(256, 4) void k_dist(
    const float* __restrict__ u,      // (B,X,C) in ws
    float* __restrict__ wsd)          // [SPLIT][B][C][C] partials
{
    const int d    = threadIdx.x;
    const int c0   = blockIdx.x * TCD;
    const int b    = blockIdx.y;
    const int x0   = blockIdx.z * XH;

    // wave-uniform base for the 8 c-columns of this block's chunk
    const float* ucol = u + ((size_t)b * XX + x0) * CC + c0;
    const float* ud_ptr = u + ((size_t)b * XX + x0) * CC + d;

    float gacc0 = 0.f, gacc1 = 0.f, gacc2 = 0.f, gacc3 = 0.f;
    float gacc4 = 0.f, gacc5 = 0.f, gacc6 = 0.f, gacc7 = 0.f, sacc = 0.f;

    constexpr int NGH = XH / G;       // 8
    float b0[G], b1[G];
    ULOAD(b0, 0)
    for (int g = 0; g + 2 < NGH; g += 2) {
        ULOAD(b1, g + 1)
        UCOMP(b0, g)
        ULOAD(b0, g + 2)
        UCOMP(b1, g + 1)
    }
    ULOAD(b1, NGH - 1)
    UCOMP(b0, NGH - 2)
    UCOMP(b1, NGH - 1)

    // Exchange S so each thread sees S_c for its block's 8 c-rows.
    __shared__ float sS[CC];
    sS[d] = sacc;
    __syncthreads();

    // partial = (S_c + S_d) - 2*G  (bitwise same chain as R7 per (c,d))
    float* w = wsd + (((size_t)blockIdx.z * BB + b) * CC + c0) * CC + d;
    w[0 * CC] = fmaf(-2.0f, gacc0, __fadd_rn(sS[c0 + 0], sacc));
    w[1 * CC] = fmaf(-2.0f, gacc1, __fadd_rn(sS[c0 + 1], sacc));
    w[2 * CC] = fmaf(-2.0f, gacc2, __fadd_rn(sS[c0 + 2], sacc));
    w[3 * CC] = fmaf(-2.0f, gacc3, __fadd_rn(sS[c0 + 3], sacc));
    w[4 * CC] = fmaf(-2.0f, gacc4, __fadd_rn(sS[c0 + 4], sacc));
    w[5 * CC] = fmaf(-2.0f, gacc5, __fadd_rn(sS[c0 + 5], sacc));
    w[6 * CC] = fmaf(-2.0f, gacc6, __fadd_rn(sS[c0 + 6], sacc));
    w[7 * CC] = fmaf(-2.0f, gacc7, __fadd_rn(sS[c0 + 7], sacc));
}

__global__ __launch_bounds__(256, 4) void k_epi(
    const float* __restrict__ wsd, const float* __restrict__ A,
    const float* __restrict__ gu,  float* __restrict__ out)
{
    const int d  = threadIdx.x;
    const int c0 = blockIdx.x * TCE;
    const int b  = blockIdx.y;

    const float dAd  = A[(size_t)d * CC + d];
    const float dAd2 = __fmul_rn(dAd, dAd);

    float dist[TCE];
#pragma unroll
    for (int j = 0; j < TCE; ++j) {
        const size_t ro = ((size_t)b * CC + c0 + j) * CC + d;
        float p = wsd[ro];                                    // chunk 0
#pragma unroll
        for (int h = 1; h < SPLIT; ++h)
            p = __fadd_rn(p, wsd[(size_t)h * BB * CC * CC + ro]);
        dist[j] = __fmul_rn(dAd2, p);
    }

    float ed[TCE];
#pragma unroll
    for (int j = 0; j < TCE; ++j)
        ed[j] = (d == c0 + j) ? 0.0f : __fdiv_rn(1.0f, __fadd_rn(dist[j], 1e-10f));

    __shared__ float wmax[TCE][4];
    const int wave = threadIdx.x >> 6;
    const int lane = threadIdx.x & 63;
#pragma unroll
    for (int j = 0; j < TCE; ++j) {
        float v = ed[j];
#pragma unroll
        for (int m = 1; m < 64; m <<= 1) v = fmaxf(v, __shfl_xor(v, m));
        if (lane == 0) wmax[j][wave] = v;
    }
    __syncthreads();

#pragma unroll
    for (int j = 0; j < TCE; ++j) {
        const int c = c0 + j;
        float em = fmaxf(fmaxf(wmax[j][0], wmax[j][1]), fmaxf(wmax[j][2], wmax[j][3]));
        float p;
        if (d == c) {
            p = 0.99f;
        } else {
            p = __fmul_rn(__fdiv_rn(ed[j], em), 0.99f);
        }
        float logit = logf(__fdiv_rn(p, __fsub_rn(1.0f, p)));

        const float2 g2 = *(const float2*)(gu + (((size_t)b * CC + c) * CC + d) * 2);
        float g0 = -logf(-logf(g2.x));
        float g1 = -logf(-logf(g2.y));

        float a0 = __fadd_rn(logit, g0);
        float a1 = __fadd_rn(-logit, g1);
        float m  = fmaxf(a0, a1);
        float e0 = expf(__fsub_rn(a0, m));
        float e1 = expf(__fsub_rn(a1, m));
        float s  = __fadd_rn(e0, e1);
        float y0 = __fdiv_rn(e0, s);
        float y1 = __fdiv_rn(e1, s);
        if (y0 > y1) {
            atomicAdd(&out[(size_t)c * CC + d], 0.125f);
        }
    }
}

// ---------------- Path B: fused fallback (no ws) — R7 verbatim ----------------

#define STEPU(UC, ACC) {                         \
    float diff = __fsub_rn(UC, ud);              \
    float t    = __fmul_rn(dAd, diff);           \
    float sq   = __fmul_rn(t, t);                \
    ACC = __fadd_rn(ACC, sq);                    \
}

#define LOADG(BA, BP, GIDX) {                    \
    const float* _a = ampbd + (size_t)(GIDX) * G * CC; \
    const float* _p = phbd  + (size_t)(GIDX) * G * CC; \
    _Pragma("unroll")                            \
    for (int i = 0; i < G; ++i) {                \
        BA[i] = _a[(size_t)i * CC];              \
        BP[i] = _p[(size_t)i * CC];              \
    }                                            \
}

#define COMPG(BA, BP, GIDX) {                    \
    const int _xb = (GIDX) * G;                  \
    _Pragma("unroll")                            \
    for (int i = 0; i < G; ++i) {                \
        const float av = BA[i];                  \
        const float pv = BP[i];                  \
        const float ud = __fadd_rn(__fmul_rn(wa, av), __fmul_rn(wp, pv)); \
        const float4 uc = cols[_xb + i];         \
        STEPU(uc.x, acc0)                        \
        STEPU(uc.y, acc1)                        \
        STEPU(uc.z, acc2)                        \
        STEPU(uc.w, acc3)                        \
    }                                            \
}

__global__ __launch_bounds__(256, 2) void k_fused(
    const float* __restrict__ amp, const float* __restrict__ ph,
    const float* __restrict__ A,   const float* __restrict__ wAp,
    const float* __restrict__ wPp, const float* __restrict__ gu,
    float* __restrict__ out)
{
    const int d  = threadIdx.x;
    const int c0 = blockIdx.x * TCE;
    const int b  = blockIdx.y;

    const float wa = wAp[0];
    const float wp = wPp[0];

    __shared__ float4 cols[XX];
    {
        const int x = threadIdx.x;
        const size_t base = ((size_t)b * XX + x) * CC + c0;
        const float4 a4 = *(const float4*)(amp + base);
        const float4 p4 = *(const float4*)(ph  + base);
        float4 uu;
        uu.x = __fadd_rn(__fmul_rn(wa, a4.x), __fmul_rn(wp, p4.x));
        uu.y = __fadd_rn(__fmul_rn(wa, a4.y), __fmul_rn(wp, p4.y));
        uu.z = __fadd_rn(__fmul_rn(wa, a4.z), __fmul_rn(wp, p4.z));
        uu.w = __fadd_rn(__fmul_rn(wa, a4.w), __fmul_rn(wp, p4.w));
        cols[x] = uu;
    }
    __syncthreads();

    const float dAd = A[(size_t)d * CC + d];
    const float* ampbd = amp + (size_t)b * XX * CC + d;
    const float* phbd  = ph  + (size_t)b * XX * CC + d;

    float acc0 = 0.0f, acc1 = 0.0f, acc2 = 0.0f, acc3 = 0.0f;
    constexpr int NG = XX / G;
    {
        float b0A[G], b0P[G], b1A[G], b1P[G];
        LOADG(b0A, b0P, 0)
        for (int g = 0; g + 2 < NG; g += 2) {
            LOADG(b1A, b1P, g + 1)
            COMPG(b0A, b0P, g)
            LOADG(b0A, b0P, g + 2)
            COMPG(b1A, b1P, g + 1)
        }
        LOADG(b1A, b1P, NG - 1)
        COMPG(b0A, b0P, NG - 2)
        COMPG(b1A, b1P, NG - 1)
    }

    float ed[TCE];
    ed[0] = (d == c0)     ? 0.0f : __fdiv_rn(1.0f, __fadd_rn(acc0, 1e-10f));
    ed[1] = (d == c0 + 1) ? 0.0f : __fdiv_rn(1.0f, __fadd_rn(acc1, 1e-10f));
    ed[2] = (d == c0 + 2) ? 0.0f : __fdiv_rn(1.0f, __fadd_rn(acc2, 1e-10f));
    ed[3] = (d == c0 + 3) ? 0.0f : __fdiv_rn(1.0f, __fadd_rn(acc3, 1e-10f));

    __shared__ float wmax[TCE][4];
    const int wave = threadIdx.x >> 6;
    const int lane = threadIdx.x & 63;
#pragma unroll
    for (int j = 0; j < TCE; ++j) {
        float v = ed[j];
#pragma unroll
        for (int m = 1; m < 64; m <<= 1) v = fmaxf(v, __shfl_xor(v, m));
        if (lane == 0) wmax[j][wave] = v;
    }
    __syncthreads();

#pragma unroll
    for (int j = 0; j < TCE; ++j) {
        const int c = c0 + j;
        float em = fmaxf(fmaxf(wmax[j][0], wmax[j][1]), fmaxf(wmax[j][2], wmax[j][3]));
        float p;
        if (d == c) {
            p = 0.99f;
        } else {
            p = __fmul_rn(__fdiv_rn(ed[j], em), 0.99f);
        }
        float logit = logf(__fdiv_rn(p, __fsub_rn(1.0f, p)));

        const float2 g2 = *(const float2*)(gu + (((size_t)b * CC + c) * CC + d) * 2);
        float g0 = -logf(-logf(g2.x));
        float g1 = -logf(-logf(g2.y));

        float a0 = __fadd_rn(logit, g0);
        float a1 = __fadd_rn(-logit, g1);
        float m  = fmaxf(a0, a1);
        float e0 = expf(__fsub_rn(a0, m));
        float e1 = expf(__fsub_rn(a1, m));
        float s  = __fadd_rn(e0, e1);
        float y0 = __fdiv_rn(e0, s);
        float y1 = __fdiv_rn(e1, s);
        if (y0 > y1) {
            atomicAdd(&out[(size_t)c * CC + d], 0.125f);
        }
    }
}

extern "C" void kernel_launch(void* const* d_in, const int* in_sizes, int n_in,
                              void* d_out, int out_size, void* d_ws, size_t ws_size,
                              hipStream_t stream) {
    const float* amp = (const float*)d_in[0];
    const float* ph  = (const float*)d_in[1];
    const float* A   = (const float*)d_in[2];
    const float* wa  = (const float*)d_in[3];
    const float* wp  = (const float*)d_in[4];
    const float* gu  = (const float*)d_in[5];
    float* out = (float*)d_out;

    const size_t uElems = (size_t)BB * XX * CC;                    // 2 MB
    const size_t pElems = (size_t)SPLIT * BB * CC * CC;            // 8 MB
    const size_t need = (uElems + pElems) * sizeof(float);
    if (ws_size >= need) {
        float* ud  = (float*)d_ws;          // fully written by k_u
        float* wsd = ud + uElems;           // fully written by k_dist
        k_u<<<uElems / 4 / 256, 256, 0, stream>>>(amp, ph, wa, wp, ud, out);
        dim3 g1(CC / TCD, BB, SPLIT);
        k_dist<<<g1, 256, 0, stream>>>(ud, wsd);
        dim3 g2(CC / TCE, BB);
        k_epi<<<g2, 256, 0, stream>>>(wsd, A, gu, out);
    } else {
        hipMemsetAsync(out, 0, (size_t)CC * CC * sizeof(float), stream);
        dim3 g(CC / TCE, BB);
        k_fused<<<g, 256, 0, stream>>>(amp, ph, A, wa, wp, gu, out);
    }
}